// Round 1
// 350.371 us; speedup vs baseline: 1.1196x; 1.1196x over previous
//
#include <hip/hip_runtime.h>
#include <stdint.h>

// SNN forward: conv1 -> scan -> pool1(fused) -> conv2 -> scan -> pool2(fused)
// -> conv3 -> scan -> fc(MFMA) -> reduce -> scan.
// Neuron: u=.75u+x; v=.96875v+u; s=(v>=100); v*=(1-s). Spikes u8 in d_ws.
// R9: FC GEMM moved to matrix cores. Spikes are exact in bf16 (0/1); fp32
// weights split EXACTLY into 3 bf16 planes by mantissa truncation
// (8+8+8=24 bits, zero residual) -> y = S*hi + S*mid + S*lo accumulated in
// the MFMA fp32 accumulator. Only accumulation-order rounding differs from
// the fp32 VALU version (which already reordered vs reference, absmax 0).

#define T 128
#define AI 0.75f
#define AV 0.96875f
#define THETA 100.0f

typedef __attribute__((ext_vector_type(8))) short v8s;    // 8 x bf16 bits
typedef __attribute__((ext_vector_type(16))) float v16f;  // 32x32 acc

__device__ __forceinline__ void neuron_step(float x, float& u, float& v, float& s) {
    u = AI * u + x;
    v = AV * v + u;
    s = (v >= THETA) ? 1.0f : 0.0f;
    v = v * (1.0f - s);
}

// ---------------- conv1 phase A: x[n][o][h][w][t], lanes over t -------------
__global__ __launch_bounds__(256) void conv1_x(
    const float* __restrict__ in, const float* __restrict__ cw,
    float* __restrict__ xout)
{
    int bid = blockIdx.x;                       // 12800
    int tIdx = (bid % 800) * 256 + threadIdx.x; // within [40][40][128]
    int n = bid / 800;
    int t  = tIdx % T;
    int wx = (tIdx / T) % 40;
    int hy = tIdx / (T * 40);

    float val[18];
    #pragma unroll
    for (int c = 0; c < 2; c++)
      #pragma unroll
      for (int dh = -1; dh <= 1; dh++)
        #pragma unroll
        for (int dw = -1; dw <= 1; dw++) {
            int q = c * 9 + (dh + 1) * 3 + (dw + 1);
            int hh = hy + dh, ww = wx + dw;
            bool ok = (hh >= 0) && (hh < 40) && (ww >= 0) && (ww < 40);
            val[q] = ok ? in[(((n * 2 + c) * 40 + hh) * 40 + ww) * T + t] : 0.0f;
        }

    #pragma unroll 1
    for (int o = 0; o < 8; o++) {
        const float* wp = cw + o * 18;          // uniform -> s_load
        float a = 0.f;
        #pragma unroll
        for (int q = 0; q < 18; q++) a += wp[q] * val[q];
        xout[(((n * 8 + o) * 40 + hy) * 40 + wx) * T + t] = a * 20.0f;
    }
}

// ---------------- scan (transposed via LDS): fp32 x rows -> u8 spikes -------
__global__ __launch_bounds__(256) void scan_spike_t(
    const float* __restrict__ x, uint8_t* __restrict__ out)
{
    __shared__ float lds[256 * 20];
    int tid = threadIdx.x;
    size_t r0 = (size_t)blockIdx.x * 256;
    const float* xb = x + r0 * T;

    float u = 0.f, v = 0.f;
    uint32_t ob[32];

    #pragma unroll
    for (int tb = 0; tb < 8; tb++) {
        __syncthreads();
        #pragma unroll
        for (int k = 0; k < 4; k++) {
            int f = tid + k * 256;
            int row = f >> 2, q = f & 3;
            float4 vv = *(const float4*)(xb + (size_t)row * T + tb * 16 + q * 4);
            *(float4*)&lds[row * 20 + q * 4] = vv;
        }
        __syncthreads();
        #pragma unroll
        for (int k = 0; k < 4; k++) {
            float4 xv = *(const float4*)&lds[tid * 20 + k * 4];
            float s0, s1, s2, s3;
            neuron_step(xv.x, u, v, s0); neuron_step(xv.y, u, v, s1);
            neuron_step(xv.z, u, v, s2); neuron_step(xv.w, u, v, s3);
            ob[tb * 4 + k] = (uint32_t)s0 | ((uint32_t)s1 << 8) |
                             ((uint32_t)s2 << 16) | ((uint32_t)s3 << 24);
        }
    }

    uint32_t* op = (uint32_t*)(out + (r0 + tid) * T);
    #pragma unroll
    for (int k = 0; k < 8; k++)
        *(uint4*)&op[k * 4] = make_uint4(ob[k*4], ob[k*4+1], ob[k*4+2], ob[k*4+3]);
}

// ---------------- pool fused: 2x2 sum (u8 adds, no carry) + scan + delay ----
template<int C, int HO, int WO>
__global__ __launch_bounds__(256) void pool_fused(
    const uint8_t* __restrict__ in, const float* __restrict__ pw_ptr,
    uint8_t* __restrict__ out)
{
    __shared__ uint32_t lds[256 * 20];
    int tid = threadIdx.x;
    size_t r0 = (size_t)blockIdx.x * 256;
    float pw = pw_ptr[0];

    float u = 0.f, v = 0.f;
    uint32_t ob[32];
    uint32_t carry = 0;

    #pragma unroll
    for (int tb = 0; tb < 2; tb++) {
        __syncthreads();
        #pragma unroll
        for (int k = 0; k < 4; k++) {
            int f = tid + k * 256;
            int row = f >> 2, q = f & 3;
            int orow = (int)r0 + row;
            int wx = orow % WO;
            int hy = (orow / WO) % HO;
            int c  = (orow / (WO * HO)) % C;
            int nn = orow / (WO * HO * C);
            const uint8_t* p00 = in +
                (((size_t)(nn * C + c) * (2 * HO) + 2 * hy) * (2 * WO) + 2 * wx) * T;
            int off = tb * 64 + q * 16;
            uint4 a = *(const uint4*)(p00 + off);
            uint4 b = *(const uint4*)(p00 + T + off);
            uint4 cc = *(const uint4*)(p00 + 2 * WO * T + off);
            uint4 d = *(const uint4*)(p00 + 2 * WO * T + T + off);
            *(uint4*)&lds[row * 20 + q * 4] =
                make_uint4(a.x + b.x + cc.x + d.x, a.y + b.y + cc.y + d.y,
                           a.z + b.z + cc.z + d.z, a.w + b.w + cc.w + d.w);
        }
        __syncthreads();
        #pragma unroll
        for (int q = 0; q < 4; q++) {
            uint4 w = *(const uint4*)&lds[tid * 20 + q * 4];
            uint32_t words[4] = {w.x, w.y, w.z, w.w};
            #pragma unroll
            for (int j = 0; j < 4; j++) {
                uint32_t cur = words[j];
                uint32_t del = (cur << 8) | carry;   // delay_shift bytes
                carry = cur >> 24;
                float s0, s1, s2, s3;
                neuron_step(pw * (float)(del & 0xffu),         u, v, s0);
                neuron_step(pw * (float)((del >> 8) & 0xffu),  u, v, s1);
                neuron_step(pw * (float)((del >> 16) & 0xffu), u, v, s2);
                neuron_step(pw * (float)((del >> 24) & 0xffu), u, v, s3);
                ob[tb * 16 + q * 4 + j] = (uint32_t)s0 | ((uint32_t)s1 << 8) |
                                          ((uint32_t)s2 << 16) | ((uint32_t)s3 << 24);
            }
        }
    }

    uint32_t* op = (uint32_t*)(out + (r0 + tid) * T);
    #pragma unroll
    for (int k = 0; k < 8; k++)
        *(uint4*)&op[k * 4] = make_uint4(ob[k*4], ob[k*4+1], ob[k*4+2], ob[k*4+3]);
}

// ---------------- conv phase A (grouped): COUT_PER outputs per thread -------
template<int CIN, int COUT_PER, int G, int H, int W>
__global__ __launch_bounds__(256) void conv_x_all(
    const uint8_t* __restrict__ in, const float* __restrict__ cw, float scale,
    float* __restrict__ xout)
{
    constexpr int BPG = H * W * T / 256;
    int bid = blockIdx.x;
    int tIdx = (bid % BPG) * 256 + threadIdx.x;
    int gn = bid / BPG;
    int g = gn % G;                             // uniform
    int n = gn / G;                             // uniform
    int t  = tIdx % T;
    int wx = (tIdx / T) % W;
    int hy = tIdx / (T * W);

    int tm = (t == 0) ? 0 : (t - 1);
    float tmask = (t == 0) ? 0.0f : 1.0f;

    bool okh[3] = {hy > 0, true, hy < H - 1};
    bool okw[3] = {wx > 0, true, wx < W - 1};

    const uint8_t* base = in + ((n * CIN * H + hy) * W + wx) * T + tm;
    const float* wbase = cw + g * COUT_PER * CIN * 9;

    float acc[COUT_PER];
    #pragma unroll
    for (int oi = 0; oi < COUT_PER; oi++) acc[oi] = 0.f;

    #pragma unroll 1
    for (int c = 0; c < CIN; c++) {
        float tap[9];
        #pragma unroll
        for (int dh = 0; dh < 3; dh++)
            #pragma unroll
            for (int dw = 0; dw < 3; dw++) {
                bool ok = okh[dh] && okw[dw];
                tap[dh * 3 + dw] = ok ?
                    (float)base[(c * H * W + (dh - 1) * W + (dw - 1)) * T] : 0.f;
            }
        #pragma unroll
        for (int oi = 0; oi < COUT_PER; oi++) {
            if ((oi & 3) == 0) __builtin_amdgcn_sched_barrier(0);
            const float* wp = wbase + (oi * CIN + c) * 9;
            float a = acc[oi];
            #pragma unroll
            for (int q = 0; q < 9; q++) a += wp[q] * tap[q];
            acc[oi] = a;
        }
    }

    float sm = scale * tmask;
    #pragma unroll
    for (int oi = 0; oi < COUT_PER; oi++) {
        int o = g * COUT_PER + oi;
        xout[((n * (G * COUT_PER) + o) * H * W + hy * W + wx) * T + t] = acc[oi] * sm;
    }
}

// ---------------- wsplit: fcw[512][3200] -> 3 exact bf16 planes -------------
// w = hi + mid + lo exactly (mantissa truncation 8+8+8 = 24 bits).
__global__ __launch_bounds__(256) void wsplit(
    const float* __restrict__ fw, uint16_t* __restrict__ bs)
{
    int i = blockIdx.x * 256 + threadIdx.x;      // 409,600 threads, 4 elems each
    float4 wv = *(const float4*)(fw + i * 4);
    float w4[4] = {wv.x, wv.y, wv.z, wv.w};
    uint16_t h[4], m[4], l[4];
    #pragma unroll
    for (int j = 0; j < 4; j++) {
        uint32_t b0 = __float_as_uint(w4[j]);
        h[j] = (uint16_t)(b0 >> 16);
        float r1 = w4[j] - __uint_as_float(b0 & 0xFFFF0000u);   // exact
        uint32_t b1 = __float_as_uint(r1);
        m[j] = (uint16_t)(b1 >> 16);
        float r2 = r1 - __uint_as_float(b1 & 0xFFFF0000u);      // exact
        l[j] = (uint16_t)(__float_as_uint(r2) >> 16);           // exact (<=8 bits)
    }
    *(ushort4*)(bs +       0 + i * 4) = make_ushort4(h[0], h[1], h[2], h[3]);
    *(ushort4*)(bs + 1638400 + i * 4) = make_ushort4(m[0], m[1], m[2], m[3]);
    *(ushort4*)(bs + 3276800 + i * 4) = make_ushort4(l[0], l[1], l[2], l[3]);
}

// ---------------- sT: s5 u8 [16][3200][128] -> At bf16 [16][128][3200] ------
// Transpose + delay_shift baked in: At[n][t][c] = s5[n][c][t-1], t=0 -> 0.
__global__ __launch_bounds__(256) void sT_bf16(
    const uint8_t* __restrict__ s5, uint16_t* __restrict__ At)
{
    __shared__ uint8_t tile[64 * 132];           // 64 c-rows x 128 t (+4 pad)
    int bid = blockIdx.x;                        // 800 = 16 n x 50 chunks
    int n = bid / 50;
    int c0 = (bid % 50) * 64;
    int tid = threadIdx.x;
    {
        int row = tid >> 2, q = tid & 3;
        const uint8_t* src = s5 + ((size_t)(n * 3200 + c0 + row)) * T + q * 32;
        *(uint4*)&tile[row * 132 + q * 32]      = *(const uint4*)src;
        *(uint4*)&tile[row * 132 + q * 32 + 16] = *(const uint4*)(src + 16);
    }
    __syncthreads();
    int t = tid >> 1, half = tid & 1;
    uint32_t wb[16];
    if (t == 0) {
        #pragma unroll
        for (int j = 0; j < 16; j++) wb[j] = 0u;
    } else {
        #pragma unroll
        for (int j = 0; j < 16; j++) {
            uint32_t lo = tile[(half * 32 + 2 * j) * 132 + (t - 1)] ? 0x3F80u : 0u;
            uint32_t hi = tile[(half * 32 + 2 * j + 1) * 132 + (t - 1)] ? 0x3F80u : 0u;
            wb[j] = lo | (hi << 16);
        }
    }
    uint16_t* dst = At + ((size_t)(n * 128 + t)) * 3200 + c0 + half * 32;
    #pragma unroll
    for (int k = 0; k < 4; k++)
        *(uint4*)(dst + k * 8) = make_uint4(wb[k*4], wb[k*4+1], wb[k*4+2], wb[k*4+3]);
}

// ---------------- FC GEMM on matrix cores -----------------------------------
// y[n][t][o] = sum_c At[n][t][c] * (hi+mid+lo)[o][c], K-split 10 -> ypart.
// Block: 128 thr (2 waves), tile 128t x 128o, BK=64, LDS 64KB single-buffered
// (2 blocks/CU overlap staging vs compute). A/B staged via global_load_lds
// w=16 with XOR-granule swizzle (g ^= row&7) applied on the per-lane SOURCE
// address; frag ds_read_b128 applies the same XOR -> conflict-free.
#define GLDS16(g, s) __builtin_amdgcn_global_load_lds( \
    (const __attribute__((address_space(1))) uint32_t*)(g), \
    (__attribute__((address_space(3))) uint32_t*)(s), 16, 0, 0)

__global__ __launch_bounds__(128, 2) void fc_gemm_mfma(
    const uint16_t* __restrict__ At,   // [16][128][3200] bf16
    const uint16_t* __restrict__ Bs,   // [3][512][3200] bf16
    float* __restrict__ ypart)         // [10][16][128][512] f32
{
    __shared__ uint8_t lds[65536];     // A [128][64]bf16 @0; B 3x[128][64] @16K
    int bid = blockIdx.x;              // 640 = 10ks x 4ob x 16n (n fastest)
    int n  = bid & 15;
    int ob = (bid >> 4) & 3;
    int ks = bid >> 6;
    int o0 = ob * 128;
    int cbase = ks * 320;

    int tid = threadIdx.x;
    int w = tid >> 6;                  // wave 0/1 -> o-half
    int lane = tid & 63;
    int l31 = lane & 31;
    int lhi = lane >> 5;               // k-half within frag
    int rb = lane >> 3;                // staging: row-in-8
    int gsw = (lane & 7) ^ (rb & 7);   // pre-swizzled source granule

    v16f acc[4][2];
    #pragma unroll
    for (int mi = 0; mi < 4; mi++)
        #pragma unroll
        for (int ni = 0; ni < 2; ni++)
            #pragma unroll
            for (int e = 0; e < 16; e++) acc[mi][ni][e] = 0.0f;

    const uint16_t* Abase = At + (size_t)(n * 128) * 3200 + gsw * 8;

    for (int kc = 0; kc < 5; kc++) {
        int c0 = cbase + kc * 64;
        // ---- stage A: this wave covers rows [w*64, w*64+64) ----
        #pragma unroll
        for (int i = 0; i < 8; i++) {
            int t = w * 64 + i * 8 + rb;
            const uint16_t* src = Abase + (size_t)t * 3200 + c0;
            GLDS16(src, lds + w * 8192 + i * 1024);
        }
        // ---- stage B: this wave covers 24KB of the 48KB ----
        #pragma unroll
        for (int j = 0; j < 24; j++) {
            int f0 = w * 24576 + j * 1024;
            int s = f0 >> 14;                    // split plane
            int r = ((f0 & 16383) >> 7) + rb;    // o-local row
            const uint16_t* src = Bs + (size_t)(s * 512 + o0 + r) * 3200
                                     + c0 + gsw * 8;
            GLDS16(src, lds + 16384 + f0);
        }
        __syncthreads();                         // drains vmcnt before barrier
        // ---- compute: 4 kf x (3 splits x 2 ni x 4 mi) MFMA ----
        #pragma unroll
        for (int kf = 0; kf < 4; kf++) {
            int gc = kf * 2 + lhi;
            v8s av[4];
            #pragma unroll
            for (int mi = 0; mi < 4; mi++) {
                int t = mi * 32 + l31;
                av[mi] = *(const v8s*)(lds + t * 128 + ((gc ^ (t & 7)) << 4));
            }
            #pragma unroll
            for (int s = 0; s < 3; s++) {
                #pragma unroll
                for (int ni = 0; ni < 2; ni++) {
                    int r = w * 64 + ni * 32 + l31;
                    v8s bv = *(const v8s*)(lds + 16384 + s * 16384 + r * 128
                                           + ((gc ^ (r & 7)) << 4));
                    #pragma unroll
                    for (int mi = 0; mi < 4; mi++)
                        acc[mi][ni] = __builtin_amdgcn_mfma_f32_32x32x16_bf16(
                            av[mi], bv, acc[mi][ni], 0, 0, 0);
                }
            }
        }
        __syncthreads();                         // LDS safe before next stage
    }
    // ---- epilogue: C/D layout col=lane&31, row=(r&3)+8*(r>>2)+4*(lane>>5) --
    float* yp = ypart + (size_t)ks * 1048576 + (size_t)n * 65536;
    #pragma unroll
    for (int mi = 0; mi < 4; mi++)
        #pragma unroll
        for (int ni = 0; ni < 2; ni++) {
            int o = o0 + w * 64 + ni * 32 + l31;
            #pragma unroll
            for (int r = 0; r < 16; r++) {
                int trow = mi * 32 + (r & 3) + 8 * (r >> 2) + 4 * lhi;
                yp[trow * 512 + o] = acc[mi][ni][r];
            }
        }
}

// ---------------- FC partial reduce (10 partials, float4) -------------------
__global__ __launch_bounds__(256) void fc_reduce(
    const float4* __restrict__ yp, float4* __restrict__ ys)
{
    int id = blockIdx.x * 256 + threadIdx.x;          // 262,144
    float4 x = yp[id];
    #pragma unroll
    for (int k = 1; k < 10; k++) {
        float4 y = yp[(size_t)k * 262144 + id];
        x.x += y.x; x.y += y.y; x.z += y.z; x.w += y.w;
    }
    ys[id] = x;
}

__global__ __launch_bounds__(64) void fc_scan(
    const float* __restrict__ ysum,   // [16][128][512]
    float* __restrict__ out)          // [16][512][128]
{
    int id = blockIdx.x * 64 + threadIdx.x;           // 8192
    int o = id & 511;
    int n = id >> 9;
    float u = 0.f, v = 0.f;
    float prev = 0.f;                 // final delay_shift
    for (int tb = 0; tb < T / 4; tb++) {
        float b0, b1, b2, b3;
        float x, s;
        x = ysum[(n * T + tb * 4 + 0) * 512 + o]; neuron_step(x, u, v, s); b0 = prev; prev = s;
        x = ysum[(n * T + tb * 4 + 1) * 512 + o]; neuron_step(x, u, v, s); b1 = prev; prev = s;
        x = ysum[(n * T + tb * 4 + 2) * 512 + o]; neuron_step(x, u, v, s); b2 = prev; prev = s;
        x = ysum[(n * T + tb * 4 + 3) * 512 + o]; neuron_step(x, u, v, s); b3 = prev; prev = s;
        *(float4*)&out[((size_t)(n * 512 + o)) * T + tb * 4] = make_float4(b0, b1, b2, b3);
    }
}

// ---------------- launch ----------------------------------------------------
extern "C" void kernel_launch(void* const* d_in, const int* in_sizes, int n_in,
                              void* d_out, int out_size, void* d_ws, size_t ws_size,
                              hipStream_t stream) {
    const float* spike = (const float*)d_in[0];   // [16][2][40][40][128]
    const float* c1w   = (const float*)d_in[1];   // [8][2][3][3]
    const float* c2w   = (const float*)d_in[2];   // [16][8][3][3]
    const float* c3w   = (const float*)d_in[3];   // [32][16][3][3]
    const float* p1w   = (const float*)d_in[4];   // scalar
    const float* p2w   = (const float*)d_in[5];   // scalar
    const float* fcw   = (const float*)d_in[6];   // [512][3200]
    float* out = (float*)d_out;                   // [16][512][128]

    char* ws = (char*)d_ws;
    // spike buffers
    uint8_t* s1 = (uint8_t*)(ws);                 // 26,214,400
    uint8_t* s2 = (uint8_t*)(ws + 26214400);      //  6,553,600
    uint8_t* s3 = (uint8_t*)(ws + 32768000);      // 13,107,200
    uint8_t* s4 = (uint8_t*)(ws + 45875200);      //  3,276,800
    uint8_t* s5 = (uint8_t*)(ws + 49152000);      //  6,553,600 (ends 55,705,600)
    // region @55,705,600: xbuf1 (conv1 x, 104,857,600, dead after scan s1)
    // -> xbuf (conv2/3 x, 52,428,800, ends 108,134,400)
    // -> ypart (41,943,040, ends 97,648,640). Sequentially dead, safe aliases.
    float* xbuf1 = (float*)(ws + 55705600);
    float* xbuf  = (float*)(ws + 55705600);
    float* ypart = (float*)(ws + 55705600);
    // At/Bs live after xbuf1 is dead, above the conv2/3 xbuf extent:
    uint16_t* At16 = (uint16_t*)(ws + 108134400); // 13,107,200 (ends 121,241,600)
    float* ysumb   = (float*)(ws + 122814464);    //  4,194,304 (ends 127,008,768)
    uint16_t* Bs16 = (uint16_t*)(ws + 127008768); //  9,830,400 (ends 136,839,168)

    conv1_x<<<12800, 256, 0, stream>>>(spike, c1w, xbuf1);
    scan_spike_t<<<800, 256, 0, stream>>>(xbuf1, s1);     // xbuf1 dead after
    wsplit<<<1600, 256, 0, stream>>>(fcw, Bs16);

    pool_fused<8, 20, 20><<<200, 256, 0, stream>>>(s1, p1w, s2);
    conv_x_all<8, 16, 1, 20, 20><<<3200, 256, 0, stream>>>(s2, c2w, 100.0f, xbuf);
    scan_spike_t<<<400, 256, 0, stream>>>(xbuf, s3);

    pool_fused<16, 10, 10><<<100, 256, 0, stream>>>(s3, p2w, s4);
    conv_x_all<16, 16, 2, 10, 10><<<1600, 256, 0, stream>>>(s4, c3w, 100.0f, xbuf);
    scan_spike_t<<<200, 256, 0, stream>>>(xbuf, s5);

    sT_bf16<<<800, 256, 0, stream>>>(s5, At16);
    fc_gemm_mfma<<<640, 128, 0, stream>>>(At16, Bs16, ypart);
    fc_reduce<<<1024, 256, 0, stream>>>((const float4*)ypart, (float4*)ysumb);
    fc_scan<<<128, 64, 0, stream>>>(ysumb, out);
}

// Round 2
// 319.508 us; speedup vs baseline: 1.2277x; 1.0966x over previous
//
#include <hip/hip_runtime.h>
#include <stdint.h>

// SNN forward: conv1 -> scan -> pool1(fused) -> conv2 -> scan -> pool2(fused)
// -> conv3 -> scan -> fc(MFMA) -> reduce -> scan.
// Neuron: u=.75u+x; v=.96875v+u; s=(v>=100); v*=(1-s). Spikes u8 in d_ws.
// R9: FC GEMM on matrix cores (exact 3-way bf16 weight split).
// R10: conv2/conv3 rewritten 4-t-per-thread (conv_t4): aligned dword spike
// loads with byte-shift delay (pool_fused trick), manual c+1 prefetch so
// ~1150 VALU cycles of FMA cover the 18-load latency. Old 1-t version was
// latency-bound at 27% VALUBusy (58us each, 4-5x the FMA floor).

#define T 128
#define AI 0.75f
#define AV 0.96875f
#define THETA 100.0f

typedef __attribute__((ext_vector_type(8))) short v8s;    // 8 x bf16 bits
typedef __attribute__((ext_vector_type(16))) float v16f;  // 32x32 acc

__device__ __forceinline__ void neuron_step(float x, float& u, float& v, float& s) {
    u = AI * u + x;
    v = AV * v + u;
    s = (v >= THETA) ? 1.0f : 0.0f;
    v = v * (1.0f - s);
}

// ---------------- conv1 phase A: x[n][o][h][w][t], lanes over t -------------
__global__ __launch_bounds__(256) void conv1_x(
    const float* __restrict__ in, const float* __restrict__ cw,
    float* __restrict__ xout)
{
    int bid = blockIdx.x;                       // 12800
    int tIdx = (bid % 800) * 256 + threadIdx.x; // within [40][40][128]
    int n = bid / 800;
    int t  = tIdx % T;
    int wx = (tIdx / T) % 40;
    int hy = tIdx / (T * 40);

    float val[18];
    #pragma unroll
    for (int c = 0; c < 2; c++)
      #pragma unroll
      for (int dh = -1; dh <= 1; dh++)
        #pragma unroll
        for (int dw = -1; dw <= 1; dw++) {
            int q = c * 9 + (dh + 1) * 3 + (dw + 1);
            int hh = hy + dh, ww = wx + dw;
            bool ok = (hh >= 0) && (hh < 40) && (ww >= 0) && (ww < 40);
            val[q] = ok ? in[(((n * 2 + c) * 40 + hh) * 40 + ww) * T + t] : 0.0f;
        }

    #pragma unroll 1
    for (int o = 0; o < 8; o++) {
        const float* wp = cw + o * 18;          // uniform -> s_load
        float a = 0.f;
        #pragma unroll
        for (int q = 0; q < 18; q++) a += wp[q] * val[q];
        xout[(((n * 8 + o) * 40 + hy) * 40 + wx) * T + t] = a * 20.0f;
    }
}

// ---------------- scan (transposed via LDS): fp32 x rows -> u8 spikes -------
__global__ __launch_bounds__(256) void scan_spike_t(
    const float* __restrict__ x, uint8_t* __restrict__ out)
{
    __shared__ float lds[256 * 20];
    int tid = threadIdx.x;
    size_t r0 = (size_t)blockIdx.x * 256;
    const float* xb = x + r0 * T;

    float u = 0.f, v = 0.f;
    uint32_t ob[32];

    #pragma unroll
    for (int tb = 0; tb < 8; tb++) {
        __syncthreads();
        #pragma unroll
        for (int k = 0; k < 4; k++) {
            int f = tid + k * 256;
            int row = f >> 2, q = f & 3;
            float4 vv = *(const float4*)(xb + (size_t)row * T + tb * 16 + q * 4);
            *(float4*)&lds[row * 20 + q * 4] = vv;
        }
        __syncthreads();
        #pragma unroll
        for (int k = 0; k < 4; k++) {
            float4 xv = *(const float4*)&lds[tid * 20 + k * 4];
            float s0, s1, s2, s3;
            neuron_step(xv.x, u, v, s0); neuron_step(xv.y, u, v, s1);
            neuron_step(xv.z, u, v, s2); neuron_step(xv.w, u, v, s3);
            ob[tb * 4 + k] = (uint32_t)s0 | ((uint32_t)s1 << 8) |
                             ((uint32_t)s2 << 16) | ((uint32_t)s3 << 24);
        }
    }

    uint32_t* op = (uint32_t*)(out + (r0 + tid) * T);
    #pragma unroll
    for (int k = 0; k < 8; k++)
        *(uint4*)&op[k * 4] = make_uint4(ob[k*4], ob[k*4+1], ob[k*4+2], ob[k*4+3]);
}

// ---------------- pool fused: 2x2 sum (u8 adds, no carry) + scan + delay ----
template<int C, int HO, int WO>
__global__ __launch_bounds__(256) void pool_fused(
    const uint8_t* __restrict__ in, const float* __restrict__ pw_ptr,
    uint8_t* __restrict__ out)
{
    __shared__ uint32_t lds[256 * 20];
    int tid = threadIdx.x;
    size_t r0 = (size_t)blockIdx.x * 256;
    float pw = pw_ptr[0];

    float u = 0.f, v = 0.f;
    uint32_t ob[32];
    uint32_t carry = 0;

    #pragma unroll
    for (int tb = 0; tb < 2; tb++) {
        __syncthreads();
        #pragma unroll
        for (int k = 0; k < 4; k++) {
            int f = tid + k * 256;
            int row = f >> 2, q = f & 3;
            int orow = (int)r0 + row;
            int wx = orow % WO;
            int hy = (orow / WO) % HO;
            int c  = (orow / (WO * HO)) % C;
            int nn = orow / (WO * HO * C);
            const uint8_t* p00 = in +
                (((size_t)(nn * C + c) * (2 * HO) + 2 * hy) * (2 * WO) + 2 * wx) * T;
            int off = tb * 64 + q * 16;
            uint4 a = *(const uint4*)(p00 + off);
            uint4 b = *(const uint4*)(p00 + T + off);
            uint4 cc = *(const uint4*)(p00 + 2 * WO * T + off);
            uint4 d = *(const uint4*)(p00 + 2 * WO * T + T + off);
            *(uint4*)&lds[row * 20 + q * 4] =
                make_uint4(a.x + b.x + cc.x + d.x, a.y + b.y + cc.y + d.y,
                           a.z + b.z + cc.z + d.z, a.w + b.w + cc.w + d.w);
        }
        __syncthreads();
        #pragma unroll
        for (int q = 0; q < 4; q++) {
            uint4 w = *(const uint4*)&lds[tid * 20 + q * 4];
            uint32_t words[4] = {w.x, w.y, w.z, w.w};
            #pragma unroll
            for (int j = 0; j < 4; j++) {
                uint32_t cur = words[j];
                uint32_t del = (cur << 8) | carry;   // delay_shift bytes
                carry = cur >> 24;
                float s0, s1, s2, s3;
                neuron_step(pw * (float)(del & 0xffu),         u, v, s0);
                neuron_step(pw * (float)((del >> 8) & 0xffu),  u, v, s1);
                neuron_step(pw * (float)((del >> 16) & 0xffu), u, v, s2);
                neuron_step(pw * (float)((del >> 24) & 0xffu), u, v, s3);
                ob[tb * 16 + q * 4 + j] = (uint32_t)s0 | ((uint32_t)s1 << 8) |
                                          ((uint32_t)s2 << 16) | ((uint32_t)s3 << 24);
            }
        }
    }

    uint32_t* op = (uint32_t*)(out + (r0 + tid) * T);
    #pragma unroll
    for (int k = 0; k < 8; k++)
        *(uint4*)&op[k * 4] = make_uint4(ob[k*4], ob[k*4+1], ob[k*4+2], ob[k*4+3]);
}

// ---------------- conv phase A v2: 4 t per thread, dword loads, prefetch ----
// Block = 128 thr = 4 pixels x 32 t-threads. Delay baked in via byte shift.
template<int CIN, int COUT_PER, int G, int H, int W>
__global__ __launch_bounds__(128) void conv_t4(
    const uint8_t* __restrict__ in, const float* __restrict__ cw, float scale,
    float* __restrict__ xout)
{
    constexpr int BPG = (H * W) / 4;
    int bid = blockIdx.x;
    int pb = bid % BPG;
    int gn = bid / BPG;
    int g = gn % G;                             // uniform
    int n = gn / G;                             // uniform
    int tid = threadIdx.x;
    int p  = tid >> 5;
    int lt = tid & 31;
    int t0 = lt * 4;
    int hw = pb * 4 + p;
    int wx = hw % W, hy = hw / W;

    bool okh[3] = {hy > 0, true, hy < H - 1};
    bool okw[3] = {wx > 0, true, wx < W - 1};
    bool tok = t0 > 0;

    const uint8_t* base = in + ((size_t)(n * CIN * H + hy) * W + wx) * T + t0;
    const float* wbase = cw + g * COUT_PER * CIN * 9;

    float acc[COUT_PER][4];
    #pragma unroll
    for (int oi = 0; oi < COUT_PER; oi++)
        #pragma unroll
        for (int tt = 0; tt < 4; tt++) acc[oi][tt] = 0.f;

    uint32_t cur[9], prv[9];
    #pragma unroll
    for (int dh = 0; dh < 3; dh++)
      #pragma unroll
      for (int dw = 0; dw < 3; dw++) {
          int q = dh * 3 + dw;
          bool ok = okh[dh] && okw[dw];
          const uint8_t* pp = base + ((dh - 1) * W + (dw - 1)) * T;
          cur[q] = ok ? *(const uint32_t*)pp : 0u;
          prv[q] = (ok && tok) ? *(const uint32_t*)(pp - 4) : 0u;
      }

    #pragma unroll 1
    for (int c = 0; c < CIN; c++) {
        float f[9][4];
        #pragma unroll
        for (int q = 0; q < 9; q++) {
            uint32_t del = (cur[q] << 8) | (prv[q] >> 24);  // delayed 4 bytes
            f[q][0] = (float)(del & 0xffu);
            f[q][1] = (float)((del >> 8) & 0xffu);
            f[q][2] = (float)((del >> 16) & 0xffu);
            f[q][3] = (float)(del >> 24);
        }
        if (c + 1 < CIN) {                       // prefetch next c's taps
            const uint8_t* nb = base + (size_t)(c + 1) * (H * W * T);
            #pragma unroll
            for (int dh = 0; dh < 3; dh++)
              #pragma unroll
              for (int dw = 0; dw < 3; dw++) {
                  int q = dh * 3 + dw;
                  bool ok = okh[dh] && okw[dw];
                  const uint8_t* pp = nb + ((dh - 1) * W + (dw - 1)) * T;
                  cur[q] = ok ? *(const uint32_t*)pp : 0u;
                  prv[q] = (ok && tok) ? *(const uint32_t*)(pp - 4) : 0u;
              }
        }
        #pragma unroll
        for (int oi = 0; oi < COUT_PER; oi++) {
            const float* wp = wbase + (oi * CIN + c) * 9;   // uniform -> s_load
            #pragma unroll
            for (int q = 0; q < 9; q++) {
                #pragma unroll
                for (int tt = 0; tt < 4; tt++)
                    acc[oi][tt] += wp[q] * f[q][tt];
            }
        }
    }

    float* op = xout + ((size_t)(n * (G * COUT_PER) + g * COUT_PER) * (H * W) + hw) * T + t0;
    #pragma unroll
    for (int oi = 0; oi < COUT_PER; oi++)
        *(float4*)(op + (size_t)oi * (H * W * T)) = make_float4(
            acc[oi][0] * scale, acc[oi][1] * scale,
            acc[oi][2] * scale, acc[oi][3] * scale);
}

// ---------------- wsplit: fcw[512][3200] -> 3 exact bf16 planes -------------
// w = hi + mid + lo exactly (mantissa truncation 8+8+8 = 24 bits).
__global__ __launch_bounds__(256) void wsplit(
    const float* __restrict__ fw, uint16_t* __restrict__ bs)
{
    int i = blockIdx.x * 256 + threadIdx.x;      // 409,600 threads, 4 elems each
    float4 wv = *(const float4*)(fw + i * 4);
    float w4[4] = {wv.x, wv.y, wv.z, wv.w};
    uint16_t h[4], m[4], l[4];
    #pragma unroll
    for (int j = 0; j < 4; j++) {
        uint32_t b0 = __float_as_uint(w4[j]);
        h[j] = (uint16_t)(b0 >> 16);
        float r1 = w4[j] - __uint_as_float(b0 & 0xFFFF0000u);   // exact
        uint32_t b1 = __float_as_uint(r1);
        m[j] = (uint16_t)(b1 >> 16);
        float r2 = r1 - __uint_as_float(b1 & 0xFFFF0000u);      // exact
        l[j] = (uint16_t)(__float_as_uint(r2) >> 16);           // exact (<=8 bits)
    }
    *(ushort4*)(bs +       0 + i * 4) = make_ushort4(h[0], h[1], h[2], h[3]);
    *(ushort4*)(bs + 1638400 + i * 4) = make_ushort4(m[0], m[1], m[2], m[3]);
    *(ushort4*)(bs + 3276800 + i * 4) = make_ushort4(l[0], l[1], l[2], l[3]);
}

// ---------------- sT: s5 u8 [16][3200][128] -> At bf16 [16][128][3200] ------
// Transpose + delay_shift baked in: At[n][t][c] = s5[n][c][t-1], t=0 -> 0.
__global__ __launch_bounds__(256) void sT_bf16(
    const uint8_t* __restrict__ s5, uint16_t* __restrict__ At)
{
    __shared__ uint8_t tile[64 * 132];           // 64 c-rows x 128 t (+4 pad)
    int bid = blockIdx.x;                        // 800 = 16 n x 50 chunks
    int n = bid / 50;
    int c0 = (bid % 50) * 64;
    int tid = threadIdx.x;
    {
        int row = tid >> 2, q = tid & 3;
        const uint8_t* src = s5 + ((size_t)(n * 3200 + c0 + row)) * T + q * 32;
        *(uint4*)&tile[row * 132 + q * 32]      = *(const uint4*)src;
        *(uint4*)&tile[row * 132 + q * 32 + 16] = *(const uint4*)(src + 16);
    }
    __syncthreads();
    int t = tid >> 1, half = tid & 1;
    uint32_t wb[16];
    if (t == 0) {
        #pragma unroll
        for (int j = 0; j < 16; j++) wb[j] = 0u;
    } else {
        #pragma unroll
        for (int j = 0; j < 16; j++) {
            uint32_t lo = tile[(half * 32 + 2 * j) * 132 + (t - 1)] ? 0x3F80u : 0u;
            uint32_t hi = tile[(half * 32 + 2 * j + 1) * 132 + (t - 1)] ? 0x3F80u : 0u;
            wb[j] = lo | (hi << 16);
        }
    }
    uint16_t* dst = At + ((size_t)(n * 128 + t)) * 3200 + c0 + half * 32;
    #pragma unroll
    for (int k = 0; k < 4; k++)
        *(uint4*)(dst + k * 8) = make_uint4(wb[k*4], wb[k*4+1], wb[k*4+2], wb[k*4+3]);
}

// ---------------- FC GEMM on matrix cores -----------------------------------
// y[n][t][o] = sum_c At[n][t][c] * (hi+mid+lo)[o][c], K-split 10 -> ypart.
// Block: 128 thr (2 waves), tile 128t x 128o, BK=64, LDS 64KB single-buffered
// (2 blocks/CU overlap staging vs compute). A/B staged via global_load_lds
// w=16 with XOR-granule swizzle (g ^= row&7) applied on the per-lane SOURCE
// address; frag ds_read_b128 applies the same XOR -> conflict-free.
#define GLDS16(g, s) __builtin_amdgcn_global_load_lds( \
    (const __attribute__((address_space(1))) uint32_t*)(g), \
    (__attribute__((address_space(3))) uint32_t*)(s), 16, 0, 0)

__global__ __launch_bounds__(128, 2) void fc_gemm_mfma(
    const uint16_t* __restrict__ At,   // [16][128][3200] bf16
    const uint16_t* __restrict__ Bs,   // [3][512][3200] bf16
    float* __restrict__ ypart)         // [10][16][128][512] f32
{
    __shared__ uint8_t lds[65536];     // A [128][64]bf16 @0; B 3x[128][64] @16K
    int bid = blockIdx.x;              // 640 = 10ks x 4ob x 16n (n fastest)
    int n  = bid & 15;
    int ob = (bid >> 4) & 3;
    int ks = bid >> 6;
    int o0 = ob * 128;
    int cbase = ks * 320;

    int tid = threadIdx.x;
    int w = tid >> 6;                  // wave 0/1 -> o-half
    int lane = tid & 63;
    int l31 = lane & 31;
    int lhi = lane >> 5;               // k-half within frag
    int rb = lane >> 3;                // staging: row-in-8
    int gsw = (lane & 7) ^ (rb & 7);   // pre-swizzled source granule

    v16f acc[4][2];
    #pragma unroll
    for (int mi = 0; mi < 4; mi++)
        #pragma unroll
        for (int ni = 0; ni < 2; ni++)
            #pragma unroll
            for (int e = 0; e < 16; e++) acc[mi][ni][e] = 0.0f;

    const uint16_t* Abase = At + (size_t)(n * 128) * 3200 + gsw * 8;

    for (int kc = 0; kc < 5; kc++) {
        int c0 = cbase + kc * 64;
        // ---- stage A: this wave covers rows [w*64, w*64+64) ----
        #pragma unroll
        for (int i = 0; i < 8; i++) {
            int t = w * 64 + i * 8 + rb;
            const uint16_t* src = Abase + (size_t)t * 3200 + c0;
            GLDS16(src, lds + w * 8192 + i * 1024);
        }
        // ---- stage B: this wave covers 24KB of the 48KB ----
        #pragma unroll
        for (int j = 0; j < 24; j++) {
            int f0 = w * 24576 + j * 1024;
            int s = f0 >> 14;                    // split plane
            int r = ((f0 & 16383) >> 7) + rb;    // o-local row
            const uint16_t* src = Bs + (size_t)(s * 512 + o0 + r) * 3200
                                     + c0 + gsw * 8;
            GLDS16(src, lds + 16384 + f0);
        }
        __syncthreads();                         // drains vmcnt before barrier
        // ---- compute: 4 kf x (3 splits x 2 ni x 4 mi) MFMA ----
        #pragma unroll
        for (int kf = 0; kf < 4; kf++) {
            int gc = kf * 2 + lhi;
            v8s av[4];
            #pragma unroll
            for (int mi = 0; mi < 4; mi++) {
                int t = mi * 32 + l31;
                av[mi] = *(const v8s*)(lds + t * 128 + ((gc ^ (t & 7)) << 4));
            }
            #pragma unroll
            for (int s = 0; s < 3; s++) {
                #pragma unroll
                for (int ni = 0; ni < 2; ni++) {
                    int r = w * 64 + ni * 32 + l31;
                    v8s bv = *(const v8s*)(lds + 16384 + s * 16384 + r * 128
                                           + ((gc ^ (r & 7)) << 4));
                    #pragma unroll
                    for (int mi = 0; mi < 4; mi++)
                        acc[mi][ni] = __builtin_amdgcn_mfma_f32_32x32x16_bf16(
                            av[mi], bv, acc[mi][ni], 0, 0, 0);
                }
            }
        }
        __syncthreads();                         // LDS safe before next stage
    }
    // ---- epilogue: C/D layout col=lane&31, row=(r&3)+8*(r>>2)+4*(lane>>5) --
    float* yp = ypart + (size_t)ks * 1048576 + (size_t)n * 65536;
    #pragma unroll
    for (int mi = 0; mi < 4; mi++)
        #pragma unroll
        for (int ni = 0; ni < 2; ni++) {
            int o = o0 + w * 64 + ni * 32 + l31;
            #pragma unroll
            for (int r = 0; r < 16; r++) {
                int trow = mi * 32 + (r & 3) + 8 * (r >> 2) + 4 * lhi;
                yp[trow * 512 + o] = acc[mi][ni][r];
            }
        }
}

// ---------------- FC partial reduce (10 partials, float4) -------------------
__global__ __launch_bounds__(256) void fc_reduce(
    const float4* __restrict__ yp, float4* __restrict__ ys)
{
    int id = blockIdx.x * 256 + threadIdx.x;          // 262,144
    float4 x = yp[id];
    #pragma unroll
    for (int k = 1; k < 10; k++) {
        float4 y = yp[(size_t)k * 262144 + id];
        x.x += y.x; x.y += y.y; x.z += y.z; x.w += y.w;
    }
    ys[id] = x;
}

__global__ __launch_bounds__(64) void fc_scan(
    const float* __restrict__ ysum,   // [16][128][512]
    float* __restrict__ out)          // [16][512][128]
{
    int id = blockIdx.x * 64 + threadIdx.x;           // 8192
    int o = id & 511;
    int n = id >> 9;
    float u = 0.f, v = 0.f;
    float prev = 0.f;                 // final delay_shift
    for (int tb = 0; tb < T / 4; tb++) {
        float b0, b1, b2, b3;
        float x, s;
        x = ysum[(n * T + tb * 4 + 0) * 512 + o]; neuron_step(x, u, v, s); b0 = prev; prev = s;
        x = ysum[(n * T + tb * 4 + 1) * 512 + o]; neuron_step(x, u, v, s); b1 = prev; prev = s;
        x = ysum[(n * T + tb * 4 + 2) * 512 + o]; neuron_step(x, u, v, s); b2 = prev; prev = s;
        x = ysum[(n * T + tb * 4 + 3) * 512 + o]; neuron_step(x, u, v, s); b3 = prev; prev = s;
        *(float4*)&out[((size_t)(n * 512 + o)) * T + tb * 4] = make_float4(b0, b1, b2, b3);
    }
}

// ---------------- launch ----------------------------------------------------
extern "C" void kernel_launch(void* const* d_in, const int* in_sizes, int n_in,
                              void* d_out, int out_size, void* d_ws, size_t ws_size,
                              hipStream_t stream) {
    const float* spike = (const float*)d_in[0];   // [16][2][40][40][128]
    const float* c1w   = (const float*)d_in[1];   // [8][2][3][3]
    const float* c2w   = (const float*)d_in[2];   // [16][8][3][3]
    const float* c3w   = (const float*)d_in[3];   // [32][16][3][3]
    const float* p1w   = (const float*)d_in[4];   // scalar
    const float* p2w   = (const float*)d_in[5];   // scalar
    const float* fcw   = (const float*)d_in[6];   // [512][3200]
    float* out = (float*)d_out;                   // [16][512][128]

    char* ws = (char*)d_ws;
    // spike buffers
    uint8_t* s1 = (uint8_t*)(ws);                 // 26,214,400
    uint8_t* s2 = (uint8_t*)(ws + 26214400);      //  6,553,600
    uint8_t* s3 = (uint8_t*)(ws + 32768000);      // 13,107,200
    uint8_t* s4 = (uint8_t*)(ws + 45875200);      //  3,276,800
    uint8_t* s5 = (uint8_t*)(ws + 49152000);      //  6,553,600 (ends 55,705,600)
    // region @55,705,600: xbuf1 (conv1 x, 104,857,600, dead after scan s1)
    // -> xbuf (conv2/3 x, 52,428,800, ends 108,134,400)
    // -> ypart (41,943,040, ends 97,648,640). Sequentially dead, safe aliases.
    float* xbuf1 = (float*)(ws + 55705600);
    float* xbuf  = (float*)(ws + 55705600);
    float* ypart = (float*)(ws + 55705600);
    // At/Bs live after xbuf1 is dead, above the conv2/3 xbuf extent:
    uint16_t* At16 = (uint16_t*)(ws + 108134400); // 13,107,200 (ends 121,241,600)
    float* ysumb   = (float*)(ws + 122814464);    //  4,194,304 (ends 127,008,768)
    uint16_t* Bs16 = (uint16_t*)(ws + 127008768); //  9,830,400 (ends 136,839,168)

    conv1_x<<<12800, 256, 0, stream>>>(spike, c1w, xbuf1);
    scan_spike_t<<<800, 256, 0, stream>>>(xbuf1, s1);     // xbuf1 dead after
    wsplit<<<1600, 256, 0, stream>>>(fcw, Bs16);

    pool_fused<8, 20, 20><<<200, 256, 0, stream>>>(s1, p1w, s2);
    conv_t4<8, 16, 1, 20, 20><<<1600, 128, 0, stream>>>(s2, c2w, 100.0f, xbuf);
    scan_spike_t<<<400, 256, 0, stream>>>(xbuf, s3);

    pool_fused<16, 10, 10><<<100, 256, 0, stream>>>(s3, p2w, s4);
    conv_t4<16, 16, 2, 10, 10><<<800, 128, 0, stream>>>(s4, c3w, 100.0f, xbuf);
    scan_spike_t<<<200, 256, 0, stream>>>(xbuf, s5);

    sT_bf16<<<800, 256, 0, stream>>>(s5, At16);
    fc_gemm_mfma<<<640, 128, 0, stream>>>(At16, Bs16, ypart);
    fc_reduce<<<1024, 256, 0, stream>>>((const float4*)ypart, (float4*)ysumb);
    fc_scan<<<128, 64, 0, stream>>>(ysumb, out);
}